// Round 5
// baseline (136.954 us; speedup 1.0000x reference)
//
#include <hip/hip_runtime.h>
#include <hip/hip_bf16.h>

// SubnetGate = gathered grouped GEMM (B=16384, K=512, N=512, E=8, col 0).
// R7: full-width gemm geometry. Evidence: gemm stuck at ~40-48us across every
// schedule (R0..R6) with all pipes <10% busy -> the flat cost is geometry,
// not schedule. Changes:
//  - gemm: BM=64 x BN=512 (full output rows per block). 256 active blocks =
//    exactly 1/CU, 8 waves; wave = 16-row stripe x 256-col half. Out rows
//    written contiguously by ONE block (R0-R6 stitched each 2KB row from 4
//    blocks at 4 times; WRITE_SIZE showed 38MB vs 32MB ideal).
//  - BK=32, 4-deep B pipeline in 128KB DYNAMIC LDS (4x32KB), global_load_lds
//    3-ahead, per-step vmcnt region-counted (A=1op, B=4ops): see table.
//  - Wtile layout [e][16kt][512n x 32k]: granule (n,g) holds W[e][kt*32+g*8
//    ..+8][n] at byte off n*64+g*16. ds_read_b128 lanes: bank = n*16+q*4
//    (mod 32) -> 2-way alias only (free). No swizzle needed.
//  - prep: scatter + xconv verbatim R6 (proven); Wtile builder rewritten.
//
// ws layout:
//   [0,      32)       int counts[8]
//   [4096,   528384)   int rowlist[8][16384]
//   [528384, 4722688)  ushort Wtile[8][16 kt][512n x 32k bf16]
//   [4722688, 21499904) ushort xg[16384][512]   (bf16 copy of x, optional)

#define NROWS   16384
#define KDIM    512
#define NDIM    512
#define NEXP    8
#define BM      64
#define BK      32
#define KT_PER  16
#define TILE_SH 16384                 // shorts per B-tile (512n x 32k) = 32KB
#define WS_ROWLIST_OFF 4096
#define WS_WT_OFF      (4096 + NEXP * NROWS * 4)
#define WS_XG_OFF      (WS_WT_OFF + (size_t)NEXP * KT_PER * TILE_SH * 2)
#define WS_NEEDED      (WS_XG_OFF + (size_t)NROWS * KDIM * 2)

typedef __bf16        bf16x8 __attribute__((ext_vector_type(8)));
typedef float         f32x4  __attribute__((ext_vector_type(4)));
typedef unsigned int  u32x4  __attribute__((ext_vector_type(4)));

__device__ __forceinline__ unsigned int f2bf_u(float f) {
    unsigned int u = __builtin_bit_cast(unsigned int, f);
    return (u + 0x7FFFu + ((u >> 16) & 1u)) >> 16;   // RNE f32->bf16
}

__device__ __forceinline__ void gl_lds16(const void* g, void* l) {
    __builtin_amdgcn_global_load_lds(
        (const __attribute__((address_space(1))) unsigned int*)g,
        (__attribute__((address_space(3))) unsigned int*)l, 16, 0, 0);
}

__device__ __forceinline__ bf16x8 pack_bf8(f32x4 lo, f32x4 hi) {
    u32x4 w;
    w.x = f2bf_u(lo.x) | (f2bf_u(lo.y) << 16);
    w.y = f2bf_u(lo.z) | (f2bf_u(lo.w) << 16);
    w.z = f2bf_u(hi.x) | (f2bf_u(hi.y) << 16);
    w.w = f2bf_u(hi.z) | (f2bf_u(hi.w) << 16);
    return __builtin_bit_cast(bf16x8, w);
}

// blocks [0,8): scatter (verbatim R6-proven): block e scans all ids, 8 iters
//   x (256 thr x 8 rows), ballot+prefix, zero atomics.
// blocks [8,136): Wtile build: block t=(e,kt) builds one 32KB tile.
// blocks [136,2184): x f32->bf16 convert into xg (16 elems/thread).
__global__ void prep_kernel(const float* __restrict__ W,
                            const float* __restrict__ x,
                            const int* __restrict__ groups,
                            int* __restrict__ counts,
                            int* __restrict__ rowlist,
                            unsigned short* __restrict__ Wtile,
                            unsigned short* __restrict__ xg) {
    const int bid = blockIdx.x;
    const int tid = threadIdx.x;

    if (bid < 8) {
        __shared__ int wcnt_s[4];
        __shared__ int woff_s[4];
        __shared__ int runb;
        const int e  = bid;
        const int w  = tid >> 6;
        const int ln = tid & 63;
        const unsigned long long below = (ln == 63) ? ~0ull >> 1
                                                    : (1ull << ln) - 1;
        int* dst = rowlist + e * NROWS;
        if (tid == 0) runb = 0;
        __syncthreads();
        for (int it = 0; it < NROWS / 2048; ++it) {      // 8 iterations
            int rbase = it * 2048 + tid * 8;
            u32x4 g0 = *(const u32x4*)&groups[rbase * 2];
            u32x4 g1 = *(const u32x4*)&groups[rbase * 2 + 4];
            u32x4 g2 = *(const u32x4*)&groups[rbase * 2 + 8];
            u32x4 g3 = *(const u32x4*)&groups[rbase * 2 + 12];
            bool h[8] = {(int)g0.x == e, (int)g0.z == e,
                         (int)g1.x == e, (int)g1.z == e,
                         (int)g2.x == e, (int)g2.z == e,
                         (int)g3.x == e, (int)g3.z == e};
            unsigned long long m[8];
            int c[8], tot = 0;
            #pragma unroll
            for (int jj = 0; jj < 8; ++jj) {
                m[jj] = __ballot(h[jj]);
                c[jj] = __popcll(m[jj]);
                tot += c[jj];
            }
            if (ln == 0) wcnt_s[w] = tot;
            __syncthreads();
            if (tid == 0) {
                int s = runb;
                #pragma unroll
                for (int i = 0; i < 4; ++i) { woff_s[i] = s; s += wcnt_s[i]; }
                runb = s;
            }
            __syncthreads();
            int base = woff_s[w];
            #pragma unroll
            for (int jj = 0; jj < 8; ++jj) {
                if (h[jj]) dst[base + __popcll(m[jj] & below)] = rbase + jj;
                base += c[jj];
            }
            __syncthreads();
        }
        if (tid == 0) counts[e] = runb;
    } else if (bid < 136) {
        // ---- W-tile build: tile t = (e, kt); [512n x 32k] granule layout.
        __shared__ __align__(16) unsigned short tl[TILE_SH];  // 32KB
        const int t  = bid - 8;
        const int e  = t >> 4;
        const int kt = t & 15;
        const float* Wb = W + (size_t)e * (KDIM * NDIM);
        #pragma unroll
        for (int it = 0; it < 8; ++it) {
            const int n = (it & 1) * 256 + tid;   // consecutive n -> coalesced
            const int g = it >> 1;                // 0..3
            const int k0 = kt * BK + g * 8;
            unsigned int p[4];
            #pragma unroll
            for (int jj = 0; jj < 4; ++jj) {
                unsigned int lo = f2bf_u(Wb[(size_t)(k0 + jj * 2) * NDIM + n]);
                unsigned int hi = f2bf_u(Wb[(size_t)(k0 + jj * 2 + 1) * NDIM + n]);
                p[jj] = lo | (hi << 16);
            }
            *(u32x4*)&tl[n * 32 + g * 8] = *(const u32x4*)p;
        }
        __syncthreads();
        unsigned short* dst = Wtile + (size_t)t * TILE_SH;
        #pragma unroll
        for (int it = 0; it < 8; ++it) {          // linear 16B copies
            int off = (it * 256 + tid) * 8;
            *(u32x4*)&dst[off] = *(const u32x4*)&tl[off];
        }
    } else {
        // ---- x -> bf16 convert (16 elems/thread, fully coalesced)
        const size_t base = ((size_t)(bid - 136) * 256 + tid) * 16;
        f32x4 v0 = *(const f32x4*)&x[base];
        f32x4 v1 = *(const f32x4*)&x[base + 4];
        f32x4 v2 = *(const f32x4*)&x[base + 8];
        f32x4 v3 = *(const f32x4*)&x[base + 12];
        *(bf16x8*)&xg[base]     = pack_bf8(v0, v1);
        *(bf16x8*)&xg[base + 8] = pack_bf8(v2, v3);
    }
}

// ---------------- gemm ----------------
// Block = (e = bid&7 -> XCD pin; mt = bid>>3). 512 thr = 8 waves.
// Wave w: m-stripe s=w>>1 (rows rb+s*16..+16), n-half nh=(w&1)*256.
// Per k-step (BK=32): 1 A-frag (lane: 16B at k=q*8 of row rl[s*16+l15]),
// 16 B-frags (ds_read_b128, 2-way bank alias = free), 16 MFMA into acc[16].
// B: 4-deep dynamic-LDS pipeline (4x32KB), staged 3 ahead; A prefetched 2
// ahead (aA/aB/aC). Per-step vmcnt VM = #vmem ops issued after B(kt)'s last
// op (A=1, B=4/step; prologue B0,B1,B2,A0,A1):
//   kt0:10 kt1:11 kt2:12 kt3..13:10 kt14:6 kt15:1.  Never drains mid-loop.
// (f32-fallback A = 2 ops/step -> actual count larger -> same VM waits
//  longer = still safe.)

extern __shared__ __align__(16) unsigned short Bsm[];   // 4 * 32KB

#define STAGE_B(KT, BUF)                                                     \
    {                                                                        \
        const unsigned short* _src = wt + (size_t)(KT) * TILE_SH;            \
        _Pragma("unroll")                                                    \
        for (int _i = 0; _i < 4; ++_i) {                                     \
            int _off = (_i * 512 + tid) * 8;                                 \
            gl_lds16(_src + _off, &Bsm[(BUF) * TILE_SH + _off]);             \
        }                                                                    \
    }

#define LOAD_A_XG(KT, AR)                                                    \
    { AR = *(const bf16x8*)(arow + (KT) * BK + q * 8); }

#define LOAD_A_F32(KT, AR)                                                   \
    {                                                                        \
        const float* _p = afrow + (KT) * BK + q * 8;                         \
        AR = pack_bf8(*(const f32x4*)_p, *(const f32x4*)(_p + 4));           \
    }

#define COMPUTE(BUF, AR)                                                     \
    {                                                                        \
        _Pragma("unroll")                                                    \
        for (int _ni = 0; _ni < 16; ++_ni) {                                 \
            int _nn = nh + _ni * 16 + l15;                                   \
            bf16x8 _bf = *(const bf16x8*)&Bsm[(BUF) * TILE_SH +              \
                                              _nn * 32 + q * 8];             \
            acc[_ni] = __builtin_amdgcn_mfma_f32_16x16x32_bf16(              \
                AR, _bf, acc[_ni], 0, 0, 0);                                 \
        }                                                                    \
    }

#define KSTEP(KT, VM, ACUR, ANXT, LOADA)                                     \
    {                                                                        \
        asm volatile("s_waitcnt vmcnt(" #VM ")" ::: "memory");               \
        __builtin_amdgcn_s_barrier();                                        \
        __builtin_amdgcn_sched_barrier(0);                                   \
        if ((KT) + 2 < KT_PER) LOADA((KT) + 2, ANXT)                         \
        if ((KT) + 3 < KT_PER) STAGE_B((KT) + 3, ((KT) + 3) & 3)             \
        __builtin_amdgcn_s_setprio(1);                                       \
        COMPUTE((KT) & 3, ACUR)                                              \
        __builtin_amdgcn_s_setprio(0);                                       \
    }

#define KLOOP(LOADA)                                                         \
    {                                                                        \
        LOADA(0, aA)                                                         \
        LOADA(1, aB)                                                         \
        KSTEP(0,  10, aA, aC, LOADA)                                         \
        KSTEP(1,  11, aB, aA, LOADA)                                         \
        KSTEP(2,  12, aC, aB, LOADA)                                         \
        KSTEP(3,  10, aA, aC, LOADA)                                         \
        KSTEP(4,  10, aB, aA, LOADA)                                         \
        KSTEP(5,  10, aC, aB, LOADA)                                         \
        KSTEP(6,  10, aA, aC, LOADA)                                         \
        KSTEP(7,  10, aB, aA, LOADA)                                         \
        KSTEP(8,  10, aC, aB, LOADA)                                         \
        KSTEP(9,  10, aA, aC, LOADA)                                         \
        KSTEP(10, 10, aB, aA, LOADA)                                         \
        KSTEP(11, 10, aC, aB, LOADA)                                         \
        KSTEP(12, 10, aA, aC, LOADA)                                         \
        KSTEP(13, 10, aB, aA, LOADA)                                         \
        KSTEP(14, 6,  aC, aB, LOADA)                                         \
        KSTEP(15, 1,  aA, aC, LOADA)                                         \
    }

__global__ __launch_bounds__(512, 2)
void gemm_kernel(const float* __restrict__ x,
                 const unsigned short* __restrict__ xg,
                 const int* __restrict__ counts,
                 const int* __restrict__ rowlist,
                 const unsigned short* __restrict__ Wtile,
                 const float* __restrict__ bias,
                 float* __restrict__ out) {
    const int bid = blockIdx.x;
    const int e   = bid & 7;
    const int mt  = bid >> 3;
    const int cnt = counts[e];
    const int rb  = mt * BM;
    if (rb >= cnt) return;
    int m_valid = cnt - rb;
    if (m_valid > BM) m_valid = BM;
    const int* rl = rowlist + e * NROWS + rb;

    const int tid = threadIdx.x;
    const int w   = tid >> 6;          // 0..7
    const int ln  = tid & 63;
    const int q   = ln >> 4;
    const int l15 = ln & 15;
    const int s   = w >> 1;            // m-stripe 0..3
    const int nh  = (w & 1) * 256;     // n-half

    const int am = s * 16 + l15;
    const int ri = (am < m_valid) ? am : 0;

    const unsigned short* wt = Wtile + (size_t)e * KT_PER * TILE_SH;

    f32x4 acc[16];
    #pragma unroll
    for (int ni = 0; ni < 16; ++ni) acc[ni] = (f32x4){0.f, 0.f, 0.f, 0.f};

    bf16x8 aA, aB, aC;

    // prologue: B(0..2) in flight, then A(0),A(1) (inside KLOOP)
    STAGE_B(0, 0)
    STAGE_B(1, 1)
    STAGE_B(2, 2)

    if (xg != nullptr) {
        const unsigned short* arow = xg + (size_t)rl[ri] * KDIM;
        KLOOP(LOAD_A_XG)
    } else {
        const float* afrow = x + (size_t)rl[ri] * KDIM;
        KLOOP(LOAD_A_F32)
    }

    // ---- epilogue: +bias, masked nontemporal stores. One block owns full
    // rows: per row this wave writes nh..nh+256 contiguously (L2 merges).
    int grow[4];
    #pragma unroll
    for (int r = 0; r < 4; ++r) {
        int mloc = s * 16 + q * 4 + r;
        grow[r] = (mloc < m_valid) ? rl[mloc] : -1;
    }
    #pragma unroll
    for (int ni = 0; ni < 16; ++ni) {
        int col = nh + ni * 16 + l15;
        float bv = bias[e * NDIM + col];
        #pragma unroll
        for (int r = 0; r < 4; ++r)
            if (grow[r] >= 0)
                __builtin_nontemporal_store(acc[ni][r] + bv,
                    &out[(size_t)grow[r] * NDIM + col]);
    }
}

extern "C" void kernel_launch(void* const* d_in, const int* in_sizes, int n_in,
                              void* d_out, int out_size, void* d_ws, size_t ws_size,
                              hipStream_t stream) {
    const float* x      = (const float*)d_in[0];   // (16384, 512) f32
    const int*   groups = (const int*)d_in[1];     // (16384, 2) i32
    const float* W      = (const float*)d_in[2];   // (8, 512, 512) f32
    const float* b      = (const float*)d_in[3];   // (8, 512) f32
    float*       out    = (float*)d_out;           // (16384, 512) f32

    char* ws = (char*)d_ws;
    int*            counts  = (int*)ws;
    int*            rowlist = (int*)(ws + WS_ROWLIST_OFF);
    unsigned short* Wtile   = (unsigned short*)(ws + WS_WT_OFF);
    const bool use_xg = (ws_size >= WS_NEEDED);
    unsigned short* xg = use_xg ? (unsigned short*)(ws + WS_XG_OFF) : nullptr;

    static bool attr_set = false;
    if (!attr_set) {
        hipFuncSetAttribute((const void*)gemm_kernel,
                            hipFuncAttributeMaxDynamicSharedMemorySize,
                            4 * TILE_SH * 2);      // 128KB dynamic LDS
        attr_set = true;
    }

    // scatter(8) + Wtile(128) + xconv(2048), 256 threads/block
    prep_kernel<<<use_xg ? 2184 : 136, 256, 0, stream>>>(
        W, x, groups, counts, rowlist, Wtile, xg);
    // 8 e x 256 mt (covers worst-case skew); inactive blocks exit on
    // counts[e]. Typical active 256 = exactly 1 block/CU, XCD-pinned.
    gemm_kernel<<<2048, 512, 4 * TILE_SH * 2, stream>>>(
        x, xg, counts, rowlist, Wtile, b, out);
}

// Round 6
// 131.128 us; speedup vs baseline: 1.0444x; 1.0444x over previous
//
#include <hip/hip_runtime.h>
#include <hip/hip_bf16.h>

// SubnetGate = gathered grouped GEMM (B=16384, K=512, N=512, E=8, col 0).
// R8: W-STATIONARY gemm. Evidence trail: gemm flat at 45-52us across R0-R7
// with all pipes <10% busy; R7 proved HBM reads irrelevant (FETCH 10MB) and
// killed the write-stitching theory (contiguous rows WORSENED writes 38->44).
// The one constant: per-k-step vmcnt+barrier with 1-2 blocks/CU = full-CU
// latency drain 8-16x per block. R8 removes the chain: stage the entire
// 512x128 W-slice (128KB, 8 swizzled kt-tiles) into LDS ONCE (one vmcnt +
// one barrier), then K=512 runs barrier-free: A prefetched 1 K-quarter ahead
// in regs, B from LDS with the R3/R6-measured conflict-free swizzle.
//  - R7's n*64+q*16 LDS layout was an 8-way bank conflict (2.1M) -> reverted
//    to the proven (g^(n&7)) granule XOR (R3: 0 conflicts).
//  - plain stores (R0's 37.8MB write regime; nontemporal measured worse).
//  - prep verbatim R6 (proven): scatter 8-iter ballot, quarter-tile Wtile
//    build (same layout gemm consumes), xconv.
//
// ws layout:
//   [0,      32)       int counts[8]
//   [4096,   528384)   int rowlist[8][16384]
//   [528384, 4722688)  ushort Wtile[8][4 nt][8 kt][128n x 64k bf16, swizzled]
//   [4722688, 21499904) ushort xg[16384][512]   (bf16 copy of x, optional)

#define NROWS   16384
#define KDIM    512
#define NDIM    512
#define NEXP    8
#define BM      256
#define BN      128
#define NT_PER  4
#define KT_PER  8
#define MC_PER  9                     // 9*256 = 2304 rows capacity (+6 sigma)
#define TILE_ELEMS (BN * 64)          // 8192 shorts = 16KB per kt-tile
#define WS_ROWLIST_OFF 4096
#define WS_WT_OFF      (4096 + NEXP * NROWS * 4)
#define WS_XG_OFF      (WS_WT_OFF + (size_t)NEXP * NT_PER * KT_PER * TILE_ELEMS * 2)
#define WS_NEEDED      (WS_XG_OFF + (size_t)NROWS * KDIM * 2)

typedef __bf16        bf16x8 __attribute__((ext_vector_type(8)));
typedef float         f32x4  __attribute__((ext_vector_type(4)));
typedef unsigned int  u32x4  __attribute__((ext_vector_type(4)));

__device__ __forceinline__ unsigned int f2bf_u(float f) {
    unsigned int u = __builtin_bit_cast(unsigned int, f);
    return (u + 0x7FFFu + ((u >> 16) & 1u)) >> 16;   // RNE f32->bf16
}

__device__ __forceinline__ void gl_lds16(const void* g, void* l) {
    __builtin_amdgcn_global_load_lds(
        (const __attribute__((address_space(1))) unsigned int*)g,
        (__attribute__((address_space(3))) unsigned int*)l, 16, 0, 0);
}

__device__ __forceinline__ bf16x8 pack_bf8(f32x4 lo, f32x4 hi) {
    u32x4 w;
    w.x = f2bf_u(lo.x) | (f2bf_u(lo.y) << 16);
    w.y = f2bf_u(lo.z) | (f2bf_u(lo.w) << 16);
    w.z = f2bf_u(hi.x) | (f2bf_u(hi.y) << 16);
    w.w = f2bf_u(hi.z) | (f2bf_u(hi.w) << 16);
    return __builtin_bit_cast(bf16x8, w);
}

// ---------------- prep (verbatim R6, proven) ----------------
__global__ void prep_kernel(const float* __restrict__ W,
                            const float* __restrict__ x,
                            const int* __restrict__ groups,
                            int* __restrict__ counts,
                            int* __restrict__ rowlist,
                            unsigned short* __restrict__ Wtile,
                            unsigned short* __restrict__ xg) {
    const int bid = blockIdx.x;
    const int tid = threadIdx.x;

    if (bid < 8) {
        __shared__ int wcnt_s[4];
        __shared__ int woff_s[4];
        __shared__ int runb;
        const int e  = bid;
        const int w  = tid >> 6;
        const int ln = tid & 63;
        const unsigned long long below = (ln == 63) ? ~0ull >> 1
                                                    : (1ull << ln) - 1;
        int* dst = rowlist + e * NROWS;
        if (tid == 0) runb = 0;
        __syncthreads();
        for (int it = 0; it < NROWS / 2048; ++it) {      // 8 iterations
            int rbase = it * 2048 + tid * 8;
            u32x4 g0 = *(const u32x4*)&groups[rbase * 2];
            u32x4 g1 = *(const u32x4*)&groups[rbase * 2 + 4];
            u32x4 g2 = *(const u32x4*)&groups[rbase * 2 + 8];
            u32x4 g3 = *(const u32x4*)&groups[rbase * 2 + 12];
            bool h[8] = {(int)g0.x == e, (int)g0.z == e,
                         (int)g1.x == e, (int)g1.z == e,
                         (int)g2.x == e, (int)g2.z == e,
                         (int)g3.x == e, (int)g3.z == e};
            unsigned long long m[8];
            int c[8], tot = 0;
            #pragma unroll
            for (int jj = 0; jj < 8; ++jj) {
                m[jj] = __ballot(h[jj]);
                c[jj] = __popcll(m[jj]);
                tot += c[jj];
            }
            if (ln == 0) wcnt_s[w] = tot;
            __syncthreads();
            if (tid == 0) {
                int s = runb;
                #pragma unroll
                for (int i = 0; i < 4; ++i) { woff_s[i] = s; s += wcnt_s[i]; }
                runb = s;
            }
            __syncthreads();
            int base = woff_s[w];
            #pragma unroll
            for (int jj = 0; jj < 8; ++jj) {
                if (h[jj]) dst[base + __popcll(m[jj] & below)] = rbase + jj;
                base += c[jj];
            }
            __syncthreads();
        }
        if (tid == 0) counts[e] = runb;
    } else if (bid < 1032) {
        // ---- W-tile build (R3/R4/R6-verified layout), quarter-tile per block
        __shared__ __align__(16) unsigned short tl4[32 * 64];  // 4KB
        const int tb   = bid - 8;
        const int tile = tb >> 2;         // e*32 + nt*8 + kt
        const int qq   = tb & 3;
        const int e  = tile >> 5;
        const int nt = (tile >> 3) & 3;
        const int kt = tile & 7;
        const float* Wb = W + (size_t)e * (KDIM * NDIM);

        const int n   = qq * 32 + (tid & 31);
        const int g   = tid >> 5;               // 0..7
        const int col = nt * BN + n;
        unsigned int p[4];
        #pragma unroll
        for (int jj = 0; jj < 4; ++jj) {
            int k0 = kt * 64 + g * 8 + jj * 2;
            unsigned int lo = f2bf_u(Wb[(size_t)k0 * NDIM + col]);
            unsigned int hi = f2bf_u(Wb[(size_t)(k0 + 1) * NDIM + col]);
            p[jj] = lo | (hi << 16);
        }
        *(u32x4*)&tl4[(n & 31) * 64 + (g ^ (n & 7)) * 8] = *(const u32x4*)p;
        __syncthreads();
        unsigned short* dst = Wtile + (size_t)tile * TILE_ELEMS
                                    + ((size_t)qq * 256 + tid) * 8;
        *(u32x4*)dst = *(const u32x4*)&tl4[tid * 8];
    } else {
        // ---- x -> bf16 convert (16 elems/thread, fully coalesced)
        const size_t base = ((size_t)(bid - 1032) * 256 + tid) * 16;
        f32x4 v0 = *(const f32x4*)&x[base];
        f32x4 v1 = *(const f32x4*)&x[base + 4];
        f32x4 v2 = *(const f32x4*)&x[base + 8];
        f32x4 v3 = *(const f32x4*)&x[base + 12];
        *(bf16x8*)&xg[base]     = pack_bf8(v0, v1);
        *(bf16x8*)&xg[base + 8] = pack_bf8(v2, v3);
    }
}

// ---------------- gemm: W-stationary ----------------
// Block = (e = bid&7 -> XCD pin; j = bid>>3: ns = j&3, mc = j>>2).
// 512 thr = 8 waves; wave w owns rows [mc*256 + w*32, +32) x 128 cols.
// Stage: full W-slice (e,ns) = 8 kt-tiles = 128KB -> dynamic LDS via
//   global_load_lds (16 iters); ONE vmcnt(8) + ONE barrier; then the whole
//   K=512 loop is barrier-free (W never changes, A in registers).
// A: per-lane 16B bf16 chunks; lane (q,l15), rows w*32+{l15, 16+l15};
//   K processed in 4 quarters of 128; next quarter's 8 loads issued before
//   current quarter's compute (compiler inserts the waits).
// B: kt-tile byte addr = kt*16KB + n*128 + ((h*4+q)^(n&7))*16 -- the
//   R3/R6-measured conflict-free swizzle.

extern __shared__ __align__(16) unsigned short Bsm[];   // 8 * 16KB = 128KB

#define LOAD_A_XG(QT, AR)                                                    \
    {                                                                        \
        _Pragma("unroll")                                                    \
        for (int _kh = 0; _kh < 4; ++_kh) {                                  \
            int _k0 = (QT) * 128 + _kh * 32 + q * 8;                         \
            AR[0][_kh] = *(const bf16x8*)(arow0 + _k0);                      \
            AR[1][_kh] = *(const bf16x8*)(arow1 + _k0);                      \
        }                                                                    \
    }

#define LOAD_A_F32(QT, AR)                                                   \
    {                                                                        \
        _Pragma("unroll")                                                    \
        for (int _kh = 0; _kh < 4; ++_kh) {                                  \
            int _k0 = (QT) * 128 + _kh * 32 + q * 8;                         \
            const float* _p0 = afrow0 + _k0;                                 \
            const float* _p1 = afrow1 + _k0;                                 \
            AR[0][_kh] = pack_bf8(*(const f32x4*)_p0, *(const f32x4*)(_p0 + 4)); \
            AR[1][_kh] = pack_bf8(*(const f32x4*)_p1, *(const f32x4*)(_p1 + 4)); \
        }                                                                    \
    }

#define COMPUTE_Q(QT, AR)                                                    \
    {                                                                        \
        _Pragma("unroll")                                                    \
        for (int _kh = 0; _kh < 4; ++_kh) {                                  \
            const int _t  = (QT) * 4 + _kh;                                  \
            const int _kt = _t >> 1;                                         \
            const int _g  = (_t & 1) * 4 + q;                                \
            _Pragma("unroll")                                                \
            for (int _ni = 0; _ni < 8; ++_ni) {                              \
                int _n = _ni * 16 + l15;                                     \
                bf16x8 _bf = *(const bf16x8*)&Bsm[_kt * TILE_ELEMS +         \
                             _n * 64 + (_g ^ (_n & 7)) * 8];                 \
                acc[0][_ni] = __builtin_amdgcn_mfma_f32_16x16x32_bf16(       \
                    AR[0][_kh], _bf, acc[0][_ni], 0, 0, 0);                  \
                acc[1][_ni] = __builtin_amdgcn_mfma_f32_16x16x32_bf16(       \
                    AR[1][_kh], _bf, acc[1][_ni], 0, 0, 0);                  \
            }                                                                \
        }                                                                    \
    }

#define KLOOP(LOADA)                                                         \
    {                                                                        \
        LOADA(1, aR)                                                         \
        COMPUTE_Q(0, aQ)                                                     \
        LOADA(2, aQ)                                                         \
        COMPUTE_Q(1, aR)                                                     \
        LOADA(3, aR)                                                         \
        COMPUTE_Q(2, aQ)                                                     \
        COMPUTE_Q(3, aR)                                                     \
    }

__global__ __launch_bounds__(512, 1)
void gemm_kernel(const float* __restrict__ x,
                 const unsigned short* __restrict__ xg,
                 const int* __restrict__ counts,
                 const int* __restrict__ rowlist,
                 const unsigned short* __restrict__ Wtile,
                 const float* __restrict__ bias,
                 float* __restrict__ out) {
    const int bid = blockIdx.x;
    const int e   = bid & 7;
    const int j   = bid >> 3;
    const int ns  = j & 3;
    const int mc  = j >> 2;
    const int cnt = counts[e];
    const int rb  = mc * BM;
    if (rb >= cnt) return;
    int m_valid = cnt - rb;
    if (m_valid > BM) m_valid = BM;
    const int* rl = rowlist + e * NROWS + rb;

    const int tid = threadIdx.x;
    const int w   = tid >> 6;          // 0..7
    const int ln  = tid & 63;
    const int q   = ln >> 4;
    const int l15 = ln & 15;
    const int wm  = w * 32;

    const unsigned short* wt =
        Wtile + (size_t)((e * NT_PER + ns) * KT_PER) * TILE_ELEMS;

    // ---- stage the whole 128KB W-slice into LDS (16 iters x 8KB)
    #pragma unroll
    for (int it = 0; it < 16; ++it) {
        int off = (it * 512 + tid) * 8;
        gl_lds16(wt + off, &Bsm[off]);
    }

    const int r0i = wm + l15;
    const int r1i = wm + 16 + l15;
    const int ri0 = (r0i < m_valid) ? r0i : 0;
    const int ri1 = (r1i < m_valid) ? r1i : 0;

    f32x4 acc[2][8];
    #pragma unroll
    for (int mi = 0; mi < 2; ++mi)
        #pragma unroll
        for (int ni = 0; ni < 8; ++ni)
            acc[mi][ni] = (f32x4){0.f, 0.f, 0.f, 0.f};

    bf16x8 aQ[2][4], aR[2][4];

    if (xg != nullptr) {
        const unsigned short* arow0 = xg + (size_t)rl[ri0] * KDIM;
        const unsigned short* arow1 = xg + (size_t)rl[ri1] * KDIM;
        LOAD_A_XG(0, aQ)           // A(q0) flies behind the 16 stage ops
        // vmcnt(8): stage ops are the first 16 in queue, A(q0) the next 8;
        // retiring down to 8 outstanding => all 16 stage ops done (in-order).
        asm volatile("s_waitcnt vmcnt(8)" ::: "memory");
        __builtin_amdgcn_s_barrier();      // all waves: LDS W-slice complete
        KLOOP(LOAD_A_XG)
    } else {
        const float* afrow0 = x + (size_t)rl[ri0] * KDIM;
        const float* afrow1 = x + (size_t)rl[ri1] * KDIM;
        LOAD_A_F32(0, aQ)          // 16 loads here -> vmcnt(16) bounds stages
        asm volatile("s_waitcnt vmcnt(16)" ::: "memory");
        __builtin_amdgcn_s_barrier();
        KLOOP(LOAD_A_F32)
    }

    // ---- epilogue: +bias, masked plain stores (C/D: col=l15, row=q*4+r)
    int grow[2][4];
    #pragma unroll
    for (int mi = 0; mi < 2; ++mi)
        #pragma unroll
        for (int r = 0; r < 4; ++r) {
            int mloc = wm + mi * 16 + q * 4 + r;
            grow[mi][r] = (mloc < m_valid) ? rl[mloc] : -1;
        }
    const int ncol0 = ns * BN;
    #pragma unroll
    for (int ni = 0; ni < 8; ++ni) {
        int col = ncol0 + ni * 16 + l15;
        float bv = bias[e * NDIM + col];
        #pragma unroll
        for (int mi = 0; mi < 2; ++mi)
            #pragma unroll
            for (int r = 0; r < 4; ++r)
                if (grow[mi][r] >= 0)
                    out[(size_t)grow[mi][r] * NDIM + col] = acc[mi][ni][r] + bv;
    }
}

extern "C" void kernel_launch(void* const* d_in, const int* in_sizes, int n_in,
                              void* d_out, int out_size, void* d_ws, size_t ws_size,
                              hipStream_t stream) {
    const float* x      = (const float*)d_in[0];   // (16384, 512) f32
    const int*   groups = (const int*)d_in[1];     // (16384, 2) i32
    const float* W      = (const float*)d_in[2];   // (8, 512, 512) f32
    const float* b      = (const float*)d_in[3];   // (8, 512) f32
    float*       out    = (float*)d_out;           // (16384, 512) f32

    char* ws = (char*)d_ws;
    int*            counts  = (int*)ws;
    int*            rowlist = (int*)(ws + WS_ROWLIST_OFF);
    unsigned short* Wtile   = (unsigned short*)(ws + WS_WT_OFF);
    const bool use_xg = (ws_size >= WS_NEEDED);
    unsigned short* xg = use_xg ? (unsigned short*)(ws + WS_XG_OFF) : nullptr;

    static bool attr_set = false;
    if (!attr_set) {
        hipFuncSetAttribute((const void*)gemm_kernel,
                            hipFuncAttributeMaxDynamicSharedMemorySize,
                            KT_PER * TILE_ELEMS * 2);      // 128KB dynamic LDS
        attr_set = true;
    }

    // scatter(8) + Wtile(1024) + xconv(2048), 256 threads/block
    prep_kernel<<<use_xg ? 3080 : 1032, 256, 0, stream>>>(
        W, x, groups, counts, rowlist, Wtile, xg);
    // 8 e x 4 ns x 9 mc = 288 blocks (~1/CU, XCD-pinned via bid&7);
    // blocks past counts[e] exit immediately.
    gemm_kernel<<<NEXP * NT_PER * MC_PER, 512, KT_PER * TILE_ELEMS * 2, stream>>>(
        x, xg, counts, rowlist, Wtile, b, out);
}